// Round 1
// baseline (31.639 us; speedup 1.0000x reference)
//
#include <hip/hip_runtime.h>

#define TPB 256
#define PT 8          // trajectory points per block

__global__ void zero_out_kernel(float* out, int n) {
    int i = blockIdx.x * blockDim.x + threadIdx.x;
    if (i < n) out[i] = 0.0f;
}

__global__ __launch_bounds__(TPB) void traj_loss_kernel(
        const float2* __restrict__ traj,
        const float2* __restrict__ obs,
        float* __restrict__ out,
        int N, int M) {
    const float HINV = 1.0f / 1024.0f;
    const int b = blockIdx.x;
    const int t = threadIdx.x;
    const int pbase = b * PT;

    // Load this block's PT trajectory points (normalized coords); every thread
    // keeps its own copy in registers (broadcast loads hit L1).
    float px[PT], py[PT];
#pragma unroll
    for (int p = 0; p < PT; ++p) {
        int idx = pbase + p;
        int cidx = idx < N ? idx : (N - 1);
        float2 tp = traj[cidx];
        if (idx < N) {
            px[p] = tp.x * HINV;
            py[p] = tp.y * HINV;
        } else {
            px[p] = 1.0e9f;   // out-of-range point -> contributes nothing
            py[p] = 1.0e9f;
        }
    }

    // Track two smallest squared distances per point.
    float m1[PT], m2[PT];
#pragma unroll
    for (int p = 0; p < PT; ++p) { m1[p] = 3.4e38f; m2[p] = 3.4e38f; }

    for (int k = t; k < M; k += TPB) {
        float2 o = obs[k];
#pragma unroll
        for (int p = 0; p < PT; ++p) {
            float dx = px[p] - o.x;
            float dy = py[p] - o.y;
            float d2 = __builtin_fmaf(dx, dx, dy * dy);
            // update (m1,m2) with value d2  (pair merge with (d2, +inf))
            float lo = fminf(m1[p], d2);
            float hi = fmaxf(m1[p], d2);
            m2[p] = fminf(m2[p], hi);
            m1[p] = lo;
        }
    }

    // Wave-level butterfly merge of (m1,m2) pairs across 64 lanes.
#pragma unroll
    for (int s = 1; s < 64; s <<= 1) {
#pragma unroll
        for (int p = 0; p < PT; ++p) {
            float o1 = __shfl_xor(m1[p], s, 64);
            float o2 = __shfl_xor(m2[p], s, 64);
            float lo = fminf(m1[p], o1);
            float hi = fmaxf(m1[p], o1);
            m2[p] = fminf(fminf(m2[p], o2), hi);
            m1[p] = lo;
        }
    }

    __shared__ float lm1[TPB / 64][PT];
    __shared__ float lm2[TPB / 64][PT];
    __shared__ float contrib[PT];
    const int wave = t >> 6;
    const int lane = t & 63;
    if (lane == 0) {
#pragma unroll
        for (int p = 0; p < PT; ++p) { lm1[wave][p] = m1[p]; lm2[wave][p] = m2[p]; }
    }
    __syncthreads();

    if (t < PT) {
        const int p = t;
        float a1 = lm1[0][p], a2 = lm2[0][p];
#pragma unroll
        for (int w = 1; w < TPB / 64; ++w) {
            float b1 = lm1[w][p], b2 = lm2[w][p];
            float lo = fminf(a1, b1);
            float hi = fmaxf(a1, b1);
            a2 = fminf(fminf(a2, b2), hi);
            a1 = lo;
        }

        float c = 0.0f;
        const int gidx = pbase + p;
        if (gidx < N) {
            float d_obs = sqrtf(a1 + 1e-6f);
            float d_sec = sqrtf(a2 + 1e-6f);
            float d_vor = 0.5f * (d_sec - d_obs);
            // obstacle term (x1000 weight folded in)
            float r = fmaxf(0.05f - d_obs, 0.0f);
            c = 1000.0f * r * r;
            // voronoi term
            if (d_obs <= 0.05f) {
                float q = d_obs - 0.05f;
                float rho = (0.1f / (0.1f + d_obs))
                          * (d_vor / (d_obs + d_vor + 1e-6f))
                          * (q * q) / (0.05f * 0.05f);
                c += rho;
            }
        }

        // Smoothness / curvature / steering for index j = gidx (j in [0, N-3]).
        if (gidx <= N - 3) {
            float2 t0 = traj[gidx];
            float2 t1 = traj[gidx + 1];
            float2 t2 = traj[gidx + 2];
            // balance: second difference, pixel coords
            float sx = t2.x - 2.0f * t1.x + t0.x;
            float sy = t2.y - 2.0f * t1.y + t0.y;
            c += sx * sx + sy * sy;
            // heading change between consecutive segments
            float d0x = t1.x - t0.x, d0y = t1.y - t0.y;
            float d1x = t2.x - t1.x, d1y = t2.y - t1.y;
            float th0 = atan2f(d0y, d0x);
            float th1 = atan2f(d1y, d1x);
            float dth = th1 - th0;
            const float PI_F = 3.14159265358979323846f;
            if (dth > PI_F) dth -= 2.0f * PI_F;
            else if (dth < -PI_F) dth += 2.0f * PI_F;
            float adth = fabsf(dth);
            float seg = sqrtf(d0x * d0x + d0y * d0y);
            float kappa = adth / (seg + 1e-6f);
            float rc = fmaxf(kappa - 0.04f, 0.0f);
            float rs = fmaxf(adth - 0.04f, 0.0f);
            c += rc * rc + rs * rs;
        }
        contrib[p] = c;
    }
    __syncthreads();

    if (t == 0) {
        float s = 0.0f;
#pragma unroll
        for (int p = 0; p < PT; ++p) s += contrib[p];
        atomicAdd(out, s);
    }
}

extern "C" void kernel_launch(void* const* d_in, const int* in_sizes, int n_in,
                              void* d_out, int out_size, void* d_ws, size_t ws_size,
                              hipStream_t stream) {
    const float2* traj = (const float2*)d_in[0];
    const float2* obs  = (const float2*)d_in[1];
    float* out = (float*)d_out;
    int N = in_sizes[0] / 2;
    int M = in_sizes[1] / 2;

    zero_out_kernel<<<1, 64, 0, stream>>>(out, out_size);

    int grid = (N + PT - 1) / PT;
    traj_loss_kernel<<<grid, TPB, 0, stream>>>(traj, obs, out, N, M);
}

// Round 2
// 28.111 us; speedup vs baseline: 1.1255x; 1.1255x over previous
//
#include <hip/hip_runtime.h>
#include <cfloat>

#define TPB 256

// ---------------------------------------------------------------------------
// Kernel 1: partial two-smallest squared distances.
// One trajectory point per THREAD; obstacle dim split into MS chunks across
// blocks. grid = PB (point blocks) * MS. No cross-lane reduction needed.
// Also zeroes out[0] (safe: final kernel launches after this one completes).
// ---------------------------------------------------------------------------
__global__ __launch_bounds__(TPB) void traj_partial_kernel(
        const float2* __restrict__ traj,
        const float4* __restrict__ obs4,   // obstacles viewed as float4 (2 pts)
        float2* __restrict__ part,         // [MS][N] partial (m1,m2) sq-dists
        float* __restrict__ out,
        int N, int M, int PB, int chunk) { // chunk is even
    const float HINV = 1.0f / 1024.0f;
    if (blockIdx.x == 0 && threadIdx.x == 0) out[0] = 0.0f;

    const int pb = blockIdx.x % PB;        // point-block
    const int c  = blockIdx.x / PB;        // obstacle chunk
    const int i  = pb * TPB + threadIdx.x; // trajectory point index
    if (i >= N) return;

    float2 tp = traj[i];
    const float px = tp.x * HINV;
    const float py = tp.y * HINV;

    float m1 = FLT_MAX, m2 = FLT_MAX;

    int k0 = c * chunk;
    int k1 = k0 + chunk; if (k1 > M) k1 = M;
    if (k0 < k1) {
        const int npairs = (k1 - k0) >> 1;
        const float4* o4 = obs4 + (k0 >> 1);
#pragma unroll 4
        for (int kp = 0; kp < npairs; ++kp) {
            float4 o = o4[kp];
            {
                float dx = px - o.x, dy = py - o.y;
                float d2 = __builtin_fmaf(dx, dx, dy * dy);
                float lo = fminf(m1, d2), hi = fmaxf(m1, d2);
                m2 = fminf(m2, hi); m1 = lo;
            }
            {
                float dx = px - o.z, dy = py - o.w;
                float d2 = __builtin_fmaf(dx, dx, dy * dy);
                float lo = fminf(m1, d2), hi = fmaxf(m1, d2);
                m2 = fminf(m2, hi); m1 = lo;
            }
        }
        if ((k1 - k0) & 1) {               // odd tail (only if M odd)
            float2 o = ((const float2*)obs4)[k1 - 1];
            float dx = px - o.x, dy = py - o.y;
            float d2 = __builtin_fmaf(dx, dx, dy * dy);
            float lo = fminf(m1, d2), hi = fmaxf(m1, d2);
            m2 = fminf(m2, hi); m1 = lo;
        }
    }
    part[c * N + i] = make_float2(m1, m2); // coalesced: consecutive i
}

// ---------------------------------------------------------------------------
// Kernel 2: merge MS partials per point, compute all loss terms, block-reduce,
// one atomicAdd per block into out[0] (zeroed by kernel 1).
// ---------------------------------------------------------------------------
__global__ __launch_bounds__(TPB) void traj_final_kernel(
        const float2* __restrict__ traj,
        const float2* __restrict__ part,   // [MS][N]
        float* __restrict__ out,
        int N, int MS) {
    const int i = blockIdx.x * TPB + threadIdx.x;
    float c = 0.0f;

    if (i < N) {
        float a1 = FLT_MAX, a2 = FLT_MAX;
        for (int ch = 0; ch < MS; ++ch) {
            float2 b = part[ch * N + i];   // coalesced
            float lo = fminf(a1, b.x), hi = fmaxf(a1, b.x);
            a2 = fminf(fminf(a2, b.y), hi);
            a1 = lo;
        }

        float d_obs = sqrtf(a1 + 1e-6f);
        float d_sec = sqrtf(a2 + 1e-6f);
        float d_vor = 0.5f * (d_sec - d_obs);
        float r = fmaxf(0.05f - d_obs, 0.0f);
        c = 1000.0f * r * r;               // obstacle term, weight folded in
        if (d_obs <= 0.05f) {
            float q = d_obs - 0.05f;
            float rho = (0.1f / (0.1f + d_obs))
                      * (d_vor / (d_obs + d_vor + 1e-6f))
                      * (q * q) / (0.05f * 0.05f);
            c += rho;                      // voronoi term
        }

        if (i <= N - 3) {                  // smoothness / curvature / steering
            float2 t0 = traj[i];
            float2 t1 = traj[i + 1];
            float2 t2 = traj[i + 2];
            float sx = t2.x - 2.0f * t1.x + t0.x;
            float sy = t2.y - 2.0f * t1.y + t0.y;
            c += sx * sx + sy * sy;
            float d0x = t1.x - t0.x, d0y = t1.y - t0.y;
            float d1x = t2.x - t1.x, d1y = t2.y - t1.y;
            float th0 = atan2f(d0y, d0x);
            float th1 = atan2f(d1y, d1x);
            float dth = th1 - th0;
            const float PI_F = 3.14159265358979323846f;
            if (dth > PI_F) dth -= 2.0f * PI_F;
            else if (dth < -PI_F) dth += 2.0f * PI_F;
            float adth = fabsf(dth);
            float seg = sqrtf(d0x * d0x + d0y * d0y);
            float kappa = adth / (seg + 1e-6f);
            float rc = fmaxf(kappa - 0.04f, 0.0f);
            float rs = fmaxf(adth - 0.04f, 0.0f);
            c += rc * rc + rs * rs;
        }
    }

    // block reduction: wave shfl + LDS across waves
    float v = c;
#pragma unroll
    for (int s = 32; s > 0; s >>= 1) v += __shfl_down(v, s, 64);
    __shared__ float bsum[TPB / 64];
    const int wave = threadIdx.x >> 6;
    const int lane = threadIdx.x & 63;
    if (lane == 0) bsum[wave] = v;
    __syncthreads();
    if (threadIdx.x == 0) {
        float s = 0.0f;
#pragma unroll
        for (int w = 0; w < TPB / 64; ++w) s += bsum[w];
        atomicAdd(out, s);
    }
}

extern "C" void kernel_launch(void* const* d_in, const int* in_sizes, int n_in,
                              void* d_out, int out_size, void* d_ws, size_t ws_size,
                              hipStream_t stream) {
    const float2* traj = (const float2*)d_in[0];
    const float4* obs4 = (const float4*)d_in[1];
    float* out = (float*)d_out;
    int N = in_sizes[0] / 2;
    int M = in_sizes[1] / 2;

    int PB = (N + TPB - 1) / TPB;          // point blocks (8 for N=2048)

    // obstacle-chunk count, capped so partials fit in d_ws
    int MS = 128;
    while (MS > 1 && (size_t)MS * (size_t)N * sizeof(float2) > ws_size) MS >>= 1;
    int chunk = (M + MS - 1) / MS;
    chunk += (chunk & 1);                  // keep even for float4 alignment

    float2* part = (float2*)d_ws;

    traj_partial_kernel<<<PB * MS, TPB, 0, stream>>>(traj, obs4, part, out,
                                                     N, M, PB, chunk);
    traj_final_kernel<<<PB, TPB, 0, stream>>>(traj, part, out, N, MS);
}